// Round 5
// baseline (679.394 us; speedup 1.0000x reference)
//
#include <hip/hip_runtime.h>
#include <math.h>

namespace {
constexpr int B_ = 32, S_ = 1024, D_ = 256, N_ = 32, C_ = 64;
constexpr int NC_ = N_ * C_;  // 2048
constexpr int XP_ = 16;       // s-chunks per b (64 rows each) for stage kernel

typedef __bf16 bf16x8 __attribute__((ext_vector_type(8)));
typedef float floatx4 __attribute__((ext_vector_type(4)));

constexpr int TS_ = 264;   // t_lds row stride (bf16): 528 B rows, 16B-mult
constexpr int CSK_ = 40;   // c_nk row stride (bf16): 80 B rows, 16B-mult
constexpr int YS_ = 258;   // y_lds row stride (fp32): 4-way max on ds_add
}  // namespace

// K1: stage. Per (b, s-chunk of 64): xsum partials + transposed bf16 x.
// thread t <-> d-column; reads coalesced (lane=d), writes xT[d][s] contiguous.
extern "C" __global__ __launch_bounds__(256) void k_stage(
    const float* __restrict__ x, float* __restrict__ xsum_part,
    __bf16* __restrict__ xT) {
  const int b = blockIdx.x, ch = blockIdx.y, t = threadIdx.x;  // t = d
  const float* xb = x + ((size_t)b * S_ + ch * 64) * D_ + t;
  bf16x8 cv[8];
  float sum = 0.f;
#pragma unroll
  for (int s = 0; s < 64; ++s) {
    float v = xb[s * D_];
    sum += v;
    cv[s >> 3][s & 7] = (__bf16)v;
  }
  xsum_part[((size_t)b * XP_ + ch) * D_ + t] = sum;
  __bf16* o = xT + ((size_t)b * D_ + t) * S_ + ch * 64;
#pragma unroll
  for (int j = 0; j < 8; ++j) *(bf16x8*)(o + j * 8) = cv[j];
}

// K2: transpose W[n][d][c] -> WT[n][c][d] (fp32) so the small-phase s-GEMV
// can read W rows as float4. Tiny (2 MB each way), runs once.
extern "C" __global__ __launch_bounds__(256) void k_wt(
    const float* __restrict__ W, float* __restrict__ WT) {
  const int n = blockIdx.x, t = threadIdx.x;
  const int c = t & 63, dq = t >> 6;
  const float* Wn = W + (size_t)n * (D_ * C_);
  float* WTn = WT + (size_t)n * (D_ * C_);
#pragma unroll 4
  for (int dd = 0; dd < 64; ++dd) {
    int d = dq * 64 + dd;
    WTn[c * D_ + d] = Wn[d * C_ + c];  // read coalesced over c
  }
}

// K3: whole routing chain for one batch per block. 512 threads = 8 waves;
// wave w owns s-window [w*128, w*128+128) in the passes and capsules
// n = 4w..4w+3 in the small phases. y, t(hi/lo), v, xsum all in LDS ->
// only __syncthreads(); no grid sync, no fences, no global atomics.
extern "C" __global__ __launch_bounds__(512, 2) void k_route(
    const float* __restrict__ x, const float* __restrict__ W,
    const float* __restrict__ WT, const __bf16* __restrict__ xT,
    const float* __restrict__ xsum_part, float* __restrict__ out) {
  __shared__ __align__(16) __bf16 th_lds[N_ * TS_];      // 16896 B
  __shared__ __align__(16) __bf16 tl_lds[N_ * TS_];      // 16896 B
  __shared__ __align__(16) __bf16 c_h[8 * N_ * CSK_];    // 20480 B (per-wave)
  __shared__ __align__(16) __bf16 c_l[8 * N_ * CSK_];    // 20480 B
  __shared__ __align__(16) float y_lds[N_ * YS_];        // 33024 B
  __shared__ __align__(16) float v_lds[N_ * C_];         // 8192 B
  __shared__ __align__(16) float xs_lds[D_];             // 1024 B

  const int b = blockIdx.x;
  const int t = threadIdx.x, w = t >> 6, lane = t & 63;
  const int quad = lane >> 4, l16 = lane & 15;

  // ---- phase X: xsum reduce + zero y ---------------------------------------
  if (t < D_) {
    float a = 0.f;
    const float* p = xsum_part + (size_t)b * XP_ * D_ + t;
#pragma unroll
    for (int q = 0; q < XP_; ++q) a += p[q * D_];
    xs_lds[t] = a;
  }
  for (int i = t; i < N_ * YS_; i += 512) y_lds[i] = 0.f;
  __syncthreads();

  float t_fp[4][4];  // running t (fp32) for this wave's 4 capsules x 4 d-slots

  // small phase: s[n,c]=scale*z@W[n] -> v=squash(s); iter<2: t += W[n]@v,
  // t -> hi/lo LDS. iter==2: v -> out. Wave-local (own 4 n's) except y reads.
  auto small_phase = [&](int iter, float scale) {
#pragma unroll 1
    for (int j = 0; j < 4; ++j) {
      const int n = (w << 2) | j;
      const float4* wr = (const float4*)(WT + ((size_t)n * C_ + lane) * D_);
      float s = 0.f;
      if (iter == 0) {
#pragma unroll 16
        for (int dq4 = 0; dq4 < 64; ++dq4) {
          float4 wv = wr[dq4];
          const float* zz = xs_lds + dq4 * 4;
          s += wv.x * zz[0] + wv.y * zz[1] + wv.z * zz[2] + wv.w * zz[3];
        }
      } else {
        const float* zz0 = y_lds + n * YS_;
#pragma unroll 16
        for (int dq4 = 0; dq4 < 64; ++dq4) {
          float4 wv = wr[dq4];
          const float* zz = zz0 + dq4 * 4;
          s += wv.x * zz[0] + wv.y * zz[1] + wv.z * zz[2] + wv.w * zz[3];
        }
      }
      s *= scale;
      float sq = s * s;
#pragma unroll
      for (int m = 1; m <= 32; m <<= 1) sq += __shfl_xor(sq, m);
      float scl = sq / ((1.f + sq) * sqrtf(sq + 1e-8f));
      float v = s * scl;
      if (iter == 2) {
        out[(size_t)b * NC_ + n * C_ + lane] = v;
      } else {
        v_lds[n * C_ + lane] = v;
      }
    }
    if (iter == 2) return;
    __syncthreads();  // v_lds published (uniform; removes same-wave hazard)
#pragma unroll 1
    for (int j = 0; j < 4; ++j) {
      const int n = (w << 2) | j;
      const float4* vv = (const float4*)(v_lds + n * C_);
#pragma unroll
      for (int q = 0; q < 4; ++q) {
        const int d = q * 64 + lane;
        const float4* W4 = (const float4*)(W + ((size_t)n * D_ + d) * C_);
        float acc = 0.f;
#pragma unroll
        for (int k = 0; k < 16; ++k) {
          float4 wv = W4[k];
          float4 vq = vv[k];
          acc += wv.x * vq.x + wv.y * vq.y + wv.z * vq.z + wv.w * vq.w;
        }
        float tf = iter ? (t_fp[j][q] + acc) : acc;
        t_fp[j][q] = tf;
        __bf16 hi = (__bf16)tf;
        th_lds[n * TS_ + d] = hi;
        tl_lds[n * TS_ + d] = (__bf16)(tf - (float)hi);
      }
    }
  };

  // routing pass: per wave, 4 subchunks of 32 s:
  //   agr[n,s] = t(hi+lo) . x   (A=t from LDS, B=x fp32->bf16 from global)
  //   softmax over n -> c hi/lo -> LDS [n][k=s] (per-wave buffer)
  //   y^T[d,n] += xT . c        (A=xT bf16 from global, B=c from LDS)
  // acc2 held in regs across subchunks; one LDS ds_add reduce at the end.
  auto pass = [&]() {
    floatx4 acc2[16][2];
#pragma unroll
    for (int dt = 0; dt < 16; ++dt) {
      acc2[dt][0] = (floatx4){0.f, 0.f, 0.f, 0.f};
      acc2[dt][1] = (floatx4){0.f, 0.f, 0.f, 0.f};
    }
    const float* xg = x + ((size_t)b * S_ + w * 128) * D_;
    const __bf16* xtg = xT + (size_t)b * D_ * S_ + w * 128;
    __bf16* ch_w = c_h + w * (N_ * CSK_);
    __bf16* cl_w = c_l + w * (N_ * CSK_);
#pragma unroll 1
    for (int sc = 0; sc < 4; ++sc) {
      floatx4 accA[2][2];
      accA[0][0] = (floatx4){0.f, 0.f, 0.f, 0.f};
      accA[0][1] = (floatx4){0.f, 0.f, 0.f, 0.f};
      accA[1][0] = (floatx4){0.f, 0.f, 0.f, 0.f};
      accA[1][1] = (floatx4){0.f, 0.f, 0.f, 0.f};
#pragma unroll
      for (int k0 = 0; k0 < 256; k0 += 32) {
        const int ks = k0 + quad * 8;
        bf16x8 ah0 = *(const bf16x8*)(th_lds + l16 * TS_ + ks);
        bf16x8 al0 = *(const bf16x8*)(tl_lds + l16 * TS_ + ks);
        bf16x8 ah1 = *(const bf16x8*)(th_lds + (16 + l16) * TS_ + ks);
        bf16x8 al1 = *(const bf16x8*)(tl_lds + (16 + l16) * TS_ + ks);
#pragma unroll
        for (int jt = 0; jt < 2; ++jt) {
          const float* xr = xg + (size_t)(sc * 32 + jt * 16 + l16) * D_ + ks;
          float4 f0 = *(const float4*)xr;
          float4 f1 = *(const float4*)(xr + 4);
          bf16x8 bx;
          bx[0] = (__bf16)f0.x; bx[1] = (__bf16)f0.y;
          bx[2] = (__bf16)f0.z; bx[3] = (__bf16)f0.w;
          bx[4] = (__bf16)f1.x; bx[5] = (__bf16)f1.y;
          bx[6] = (__bf16)f1.z; bx[7] = (__bf16)f1.w;
          accA[0][jt] = __builtin_amdgcn_mfma_f32_16x16x32_bf16(ah0, bx, accA[0][jt], 0, 0, 0);
          accA[0][jt] = __builtin_amdgcn_mfma_f32_16x16x32_bf16(al0, bx, accA[0][jt], 0, 0, 0);
          accA[1][jt] = __builtin_amdgcn_mfma_f32_16x16x32_bf16(ah1, bx, accA[1][jt], 0, 0, 0);
          accA[1][jt] = __builtin_amdgcn_mfma_f32_16x16x32_bf16(al1, bx, accA[1][jt], 0, 0, 0);
        }
      }
      // softmax over n for the two s-columns this lane covers
#pragma unroll
      for (int jt = 0; jt < 2; ++jt) {
        float mx = -1e30f;
#pragma unroll
        for (int it = 0; it < 2; ++it)
#pragma unroll
          for (int r = 0; r < 4; ++r) mx = fmaxf(mx, accA[it][jt][r]);
        mx = fmaxf(mx, __shfl_xor(mx, 16));
        mx = fmaxf(mx, __shfl_xor(mx, 32));
        float e_[2][4];
        float ss = 0.f;
#pragma unroll
        for (int it = 0; it < 2; ++it)
#pragma unroll
          for (int r = 0; r < 4; ++r) {
            e_[it][r] = __expf(accA[it][jt][r] - mx);
            ss += e_[it][r];
          }
        ss += __shfl_xor(ss, 16);
        ss += __shfl_xor(ss, 32);
        float inv = 1.f / ss;
#pragma unroll
        for (int it = 0; it < 2; ++it)
#pragma unroll
          for (int r = 0; r < 4; ++r) {
            float cv = e_[it][r] * inv;
            __bf16 chi = (__bf16)cv;
            int o = (it * 16 + quad * 4 + r) * CSK_ + jt * 16 + l16;
            ch_w[o] = chi;
            cl_w[o] = (__bf16)(cv - (float)chi);
          }
      }
      // y^T GEMM for this subchunk (B-frags hoisted; A from xT, contiguous)
      bf16x8 bh0 = *(const bf16x8*)(ch_w + l16 * CSK_ + quad * 8);
      bf16x8 bl0 = *(const bf16x8*)(cl_w + l16 * CSK_ + quad * 8);
      bf16x8 bh1 = *(const bf16x8*)(ch_w + (16 + l16) * CSK_ + quad * 8);
      bf16x8 bl1 = *(const bf16x8*)(cl_w + (16 + l16) * CSK_ + quad * 8);
#pragma unroll
      for (int dt = 0; dt < 16; ++dt) {
        bf16x8 ax = *(const bf16x8*)(xtg + (size_t)(dt * 16 + l16) * S_ +
                                     sc * 32 + quad * 8);
        acc2[dt][0] = __builtin_amdgcn_mfma_f32_16x16x32_bf16(ax, bh0, acc2[dt][0], 0, 0, 0);
        acc2[dt][0] = __builtin_amdgcn_mfma_f32_16x16x32_bf16(ax, bl0, acc2[dt][0], 0, 0, 0);
        acc2[dt][1] = __builtin_amdgcn_mfma_f32_16x16x32_bf16(ax, bh1, acc2[dt][1], 0, 0, 0);
        acc2[dt][1] = __builtin_amdgcn_mfma_f32_16x16x32_bf16(ax, bl1, acc2[dt][1], 0, 0, 0);
      }
    }
    // reduce this wave's y contribution into LDS (lane: n=it*16+l16,
    // d=dt*16+quad*4+r; YS_=258 keeps ds_add conflicts <=4-way)
#pragma unroll
    for (int dt = 0; dt < 16; ++dt)
#pragma unroll
      for (int it = 0; it < 2; ++it)
#pragma unroll
        for (int r = 0; r < 4; ++r)
          atomicAdd(&y_lds[(it * 16 + l16) * YS_ + dt * 16 + quad * 4 + r],
                    acc2[dt][it][r]);
  };

  // ---- iter 0 ---------------------------------------------------------------
  small_phase(0, 1.f / 32.f);
  __syncthreads();  // th/tl visible to all waves
  pass();           // y += c1^T @ x
  __syncthreads();  // y complete
  // ---- iter 1 ---------------------------------------------------------------
  small_phase(1, 1.f);
  __syncthreads();  // all y reads done + th/tl published
  for (int i = t; i < N_ * YS_; i += 512) y_lds[i] = 0.f;
  __syncthreads();
  pass();           // y += c2^T @ x
  __syncthreads();
  // ---- iter 2 ---------------------------------------------------------------
  small_phase(2, 1.f);
}

extern "C" void kernel_launch(void* const* d_in, const int* in_sizes, int n_in,
                              void* d_out, int out_size, void* d_ws,
                              size_t ws_size, hipStream_t stream) {
  const float* x = (const float*)d_in[0];  // [B,S,D] fp32
  const float* W = (const float*)d_in[1];  // [N,D,C] fp32
  float* out = (float*)d_out;              // [B,N,C] fp32

  // ws (~18.6 MB): [xT 16M | WT 2M | xsum_part 512K]
  char* ws = (char*)d_ws;
  __bf16* xT = (__bf16*)ws;                               // [B,D,S] bf16
  float* WT = (float*)(ws + 16777216);                    // [N,C,D] fp32
  float* xsum_part = (float*)(ws + 16777216 + 2097152);   // [B,XP,D] fp32

  k_stage<<<dim3(B_, XP_), 256, 0, stream>>>(x, xsum_part, xT);
  k_wt<<<dim3(N_), 256, 0, stream>>>(W, WT);
  k_route<<<dim3(B_), 512, 0, stream>>>(x, W, WT, xT, xsum_part, out);
}

// Round 6
// 159.025 us; speedup vs baseline: 4.2723x; 4.2723x over previous
//
#include <hip/hip_runtime.h>
#include <math.h>

namespace {
constexpr int B_ = 32, S_ = 1024, D_ = 256, N_ = 32, C_ = 64;
constexpr int NC_ = N_ * C_;  // 2048
constexpr int XP_ = 16;       // s-chunks per b

typedef __bf16 bf16x8 __attribute__((ext_vector_type(8)));
typedef __bf16 bf16x4 __attribute__((ext_vector_type(4)));
typedef float floatx4 __attribute__((ext_vector_type(4)));

constexpr int XS_ = 264;  // x_lds row stride
constexpr int TS_ = 264;  // t_lds row stride
constexpr int CS_ = 72;   // c_T row stride (s 64 + 8 pad)
}  // namespace

// K1: per (b, s-chunk): xsum partials (column sums over 64 s-rows).
extern "C" __global__ __launch_bounds__(256) void k_stage(
    const float* __restrict__ x, float* __restrict__ xsum_part) {
  const int b = blockIdx.x, sb = blockIdx.y, t = threadIdx.x;
  const float* xb = x + ((size_t)b * S_ + sb * 64) * D_;
  float a = 0.f;
  #pragma unroll 8
  for (int s = 0; s < 64; ++s) a += xb[s * D_ + t];
  xsum_part[((size_t)b * XP_ + sb) * D_ + t] = a;
}

// K2 (small chain) per (b,n):
//   zloc[d] = sum_p z[...]  (P partials)
//   s[c] = scale * zloc@W[n];  v = squash(s)
//   final: write v to vout;  else: t = W[n]@v (+= old t if accum) -> fp32 + bf16 hi/lo
extern "C" __global__ __launch_bounds__(256) void k_small(
    const float* __restrict__ z, const float* __restrict__ W,
    float* __restrict__ t_fp, __bf16* __restrict__ t_bhi,
    __bf16* __restrict__ t_blo, float* __restrict__ vout,
    int P, int zb, int zp, int zn, float scale, int accum, int final_) {
  __shared__ float zloc[256];
  __shared__ float sq_red[4][64];
  __shared__ float v_lds[64];
  const int b = blockIdx.x, n = blockIdx.y, t = threadIdx.x;

  float a = 0.f;
  for (int p = 0; p < P; ++p) a += z[(size_t)b * zb + (size_t)p * zp + n * zn + t];
  zloc[t] = a;
  __syncthreads();

  const int c = t & 63, dq = t >> 6;
  const float* Wn = W + (size_t)n * (D_ * C_);
  float s = 0.f;
  #pragma unroll 8
  for (int dd = 0; dd < 64; ++dd) {
    int d = dq * 64 + dd;
    s += zloc[d] * Wn[d * 64 + c];
  }
  sq_red[dq][c] = s;
  __syncthreads();

  if (t < 64) {
    float sc = (sq_red[0][t] + sq_red[1][t] + sq_red[2][t] + sq_red[3][t]) * scale;
    float sq = sc * sc;
    #pragma unroll
    for (int m = 1; m <= 32; m <<= 1) sq += __shfl_xor(sq, m);
    float scl = sq / ((1.f + sq) * sqrtf(sq + 1e-8f));
    float v = sc * scl;
    v_lds[t] = v;
    if (final_) vout[(size_t)b * NC_ + n * 64 + t] = v;
  }
  __syncthreads();

  if (!final_) {
    const float4* W4 = (const float4*)Wn + t * 16;
    float acc = 0.f;
    #pragma unroll
    for (int q = 0; q < 16; ++q) {
      float4 wv = W4[q];
      acc += wv.x * v_lds[q * 4] + wv.y * v_lds[q * 4 + 1] +
             wv.z * v_lds[q * 4 + 2] + wv.w * v_lds[q * 4 + 3];
    }
    size_t idx = ((size_t)b * N_ + n) * D_ + t;
    float tf = acc + (accum ? t_fp[idx] : 0.f);
    t_fp[idx] = tf;
    __bf16 hi = (__bf16)tf;
    t_bhi[idx] = hi;
    t_blo[idx] = (__bf16)(tf - (float)hi);
  }
}

// K3 (routing pass) per (b, s-chunk of 64):
//   stage x fp32 -> bf16 LDS; agr[s,n] = x.t via MFMA (t bf16 hi+lo) ->
//   softmax over n -> y_part[ch] = c^T @ x via MFMA, plain coalesced stores
//   (each block owns its private partial slice -- no atomics, no y zeroing).
extern "C" __global__ __launch_bounds__(256) void k_pass(
    const float* __restrict__ x, const __bf16* __restrict__ t_bhi,
    const __bf16* __restrict__ t_blo, float* __restrict__ y_part) {
  __shared__ __align__(16) __bf16 x_lds[64 * XS_];
  __shared__ __align__(16) __bf16 th_lds[N_ * TS_];
  __shared__ __align__(16) __bf16 tl_lds[N_ * TS_];
  __shared__ __align__(16) __bf16 c_Th[N_ * CS_];
  __shared__ __align__(16) __bf16 c_Tl[N_ * CS_];
  const int b = blockIdx.x, ch = blockIdx.y;
  const int t = threadIdx.x, w = t >> 6, lane = t & 63;
  const int quad = lane >> 4, l16 = lane & 15;

  // stage t hi/lo (8192 bf16 each, per b)
  #pragma unroll
  for (int e = 0; e < 4; ++e) {
    int idx = e * 2048 + t * 8;
    int n = idx >> 8, d = idx & 255;
    *(uint4*)(th_lds + n * TS_ + d) = *(const uint4*)(t_bhi + (size_t)b * 8192 + idx);
    *(uint4*)(tl_lds + n * TS_ + d) = *(const uint4*)(t_blo + (size_t)b * 8192 + idx);
  }
  // stage x chunk: fp32 global -> bf16 LDS (same rounding as before)
  const float* xsrc = x + ((size_t)b * S_ + ch * 64) * D_;
  #pragma unroll
  for (int e = 0; e < 16; ++e) {
    int idx = e * 1024 + t * 4;
    int row = idx >> 8, col = idx & 255;
    float4 f = *(const float4*)(xsrc + idx);
    bf16x4 p4;
    p4[0] = (__bf16)f.x; p4[1] = (__bf16)f.y;
    p4[2] = (__bf16)f.z; p4[3] = (__bf16)f.w;
    *(bf16x4*)(x_lds + row * XS_ + col) = p4;
  }
  __syncthreads();

  // agreement GEMM: A=t (m=n), B=x (n'=s), K=256; wave w owns s-tile w*16
  floatx4 acc[2];
  acc[0] = (floatx4){0.f, 0.f, 0.f, 0.f};
  acc[1] = (floatx4){0.f, 0.f, 0.f, 0.f};
  const int sbase = w * 16;
  #pragma unroll
  for (int k0 = 0; k0 < 256; k0 += 32) {
    int ks = k0 + quad * 8;
    bf16x8 bfrag = *(const bf16x8*)(x_lds + (sbase + l16) * XS_ + ks);
    #pragma unroll
    for (int i = 0; i < 2; ++i) {
      bf16x8 ah = *(const bf16x8*)(th_lds + (i * 16 + l16) * TS_ + ks);
      bf16x8 al = *(const bf16x8*)(tl_lds + (i * 16 + l16) * TS_ + ks);
      acc[i] = __builtin_amdgcn_mfma_f32_16x16x32_bf16(ah, bfrag, acc[i], 0, 0, 0);
      acc[i] = __builtin_amdgcn_mfma_f32_16x16x32_bf16(al, bfrag, acc[i], 0, 0, 0);
    }
  }
  // softmax over n for s = sbase + l16
  float mx = -1e30f;
  #pragma unroll
  for (int i = 0; i < 2; ++i)
    #pragma unroll
    for (int r = 0; r < 4; ++r) mx = fmaxf(mx, acc[i][r]);
  mx = fmaxf(mx, __shfl_xor(mx, 16));
  mx = fmaxf(mx, __shfl_xor(mx, 32));
  float e_[2][4];
  float ss = 0.f;
  #pragma unroll
  for (int i = 0; i < 2; ++i)
    #pragma unroll
    for (int r = 0; r < 4; ++r) { e_[i][r] = __expf(acc[i][r] - mx); ss += e_[i][r]; }
  ss += __shfl_xor(ss, 16);
  ss += __shfl_xor(ss, 32);
  float inv = 1.f / ss;
  #pragma unroll
  for (int i = 0; i < 2; ++i)
    #pragma unroll
    for (int r = 0; r < 4; ++r) {
      float cv = e_[i][r] * inv;
      __bf16 chi = (__bf16)cv;
      int o = (i * 16 + quad * 4 + r) * CS_ + sbase + l16;
      c_Th[o] = chi;
      c_Tl[o] = (__bf16)(cv - (float)chi);
    }
  __syncthreads();

  // y GEMM: y_part[n,d] = c^T @ x; wave w owns d-range w*64
  floatx4 acc2[2][4];
  #pragma unroll
  for (int i = 0; i < 2; ++i)
    #pragma unroll
    for (int dt = 0; dt < 4; ++dt) acc2[i][dt] = (floatx4){0.f, 0.f, 0.f, 0.f};
  const int dbase = w * 64;
  #pragma unroll
  for (int k0 = 0; k0 < 64; k0 += 32) {
    int ks = k0 + quad * 8;
    bf16x8 ah[2], al[2];
    #pragma unroll
    for (int i = 0; i < 2; ++i) {
      ah[i] = *(const bf16x8*)(c_Th + (i * 16 + l16) * CS_ + ks);
      al[i] = *(const bf16x8*)(c_Tl + (i * 16 + l16) * CS_ + ks);
    }
    #pragma unroll
    for (int dt = 0; dt < 4; ++dt) {
      bf16x8 bfr;
      #pragma unroll
      for (int j8 = 0; j8 < 8; ++j8)
        bfr[j8] = x_lds[(ks + j8) * XS_ + dbase + dt * 16 + l16];
      #pragma unroll
      for (int i = 0; i < 2; ++i) {
        acc2[i][dt] = __builtin_amdgcn_mfma_f32_16x16x32_bf16(ah[i], bfr, acc2[i][dt], 0, 0, 0);
        acc2[i][dt] = __builtin_amdgcn_mfma_f32_16x16x32_bf16(al[i], bfr, acc2[i][dt], 0, 0, 0);
      }
    }
  }
  // private partial slice: plain coalesced stores, no atomics
  float* yo = y_part + ((size_t)(b * XP_ + ch) * N_) * D_;
  #pragma unroll
  for (int i = 0; i < 2; ++i)
    #pragma unroll
    for (int dt = 0; dt < 4; ++dt)
      #pragma unroll
      for (int r = 0; r < 4; ++r) {
        int n = i * 16 + quad * 4 + r;
        int d = dbase + dt * 16 + l16;
        yo[n * D_ + d] = acc2[i][dt][r];
      }
}

extern "C" void kernel_launch(void* const* d_in, const int* in_sizes, int n_in,
                              void* d_out, int out_size, void* d_ws, size_t ws_size,
                              hipStream_t stream) {
  const float* x = (const float*)d_in[0];   // [B,S,D] fp32
  const float* W = (const float*)d_in[1];   // [N,D,C] fp32
  float* out = (float*)d_out;               // [B,N,C] fp32

  // ws (~18.5 MB): [xsum_part 512K | y_part 16.78M | t_fp 1M | t_bhi 512K | t_blo 512K]
  char* ws = (char*)d_ws;
  float* xsum_part = (float*)ws;                       // [B,XP,D]
  float* y_part = (float*)(ws + 524288);               // [B,XP,N,D]
  float* t_fp = (float*)(ws + 524288 + 16777216);      // [B,N,D]
  __bf16* t_bhi = (__bf16*)(t_fp + B_ * N_ * D_);      // [B,N,D]
  __bf16* t_blo = t_bhi + B_ * N_ * D_;                // [B,N,D]

  // 1) xsum partials
  k_stage<<<dim3(B_, XP_), 256, 0, stream>>>(x, xsum_part);

  // 2) iter 0: s1=(1/N)xsum@W -> v1 -> t1
  k_small<<<dim3(B_, N_), 256, 0, stream>>>(
      xsum_part, W, t_fp, t_bhi, t_blo, nullptr,
      XP_, XP_ * D_, D_, 0, 1.f / 32.f, 0, 0);

  // 3) pass 1: y_part[ch] = c2^T @ x(chunk ch)
  k_pass<<<dim3(B_, XP_), 256, 0, stream>>>(x, t_bhi, t_blo, y_part);

  // 4) s2=sum_ch y_part@W -> v2 -> t12 = t1 + W@v2
  k_small<<<dim3(B_, N_), 256, 0, stream>>>(
      y_part, W, t_fp, t_bhi, t_blo, nullptr,
      XP_, XP_ * N_ * D_, N_ * D_, D_, 1.f, 1, 0);

  // 5) pass 2: y_part[ch] = c3^T @ x(chunk ch)
  k_pass<<<dim3(B_, XP_), 256, 0, stream>>>(x, t_bhi, t_blo, y_part);

  // 6) s3=sum_ch y_part@W -> squash -> out
  k_small<<<dim3(B_, N_), 256, 0, stream>>>(
      y_part, W, t_fp, t_bhi, t_blo, out,
      XP_, XP_ * N_ * D_, N_ * D_, D_, 1.f, 0, 1);
}